// Round 8
// baseline (164.781 us; speedup 1.0000x reference)
//
#include <hip/hip_runtime.h>

#define C_CH 256
#define T_SZ 16
#define H_SZ 64
#define W_SZ 64
#define TGN 5
#define CH 8
#define HWs (H_SZ * W_SZ)          // 4096
#define CSTR (T_SZ * HWs)          // 65536
#define NOUT 196
#define KMAX 10                    // max unique t-slices

__device__ __forceinline__ float4 ld4(const float* p) {
    return *(const float4*)p;      // 16B-aligned by construction
}

__device__ __forceinline__ int h0_of(float hs, float hbin, int g) {
    return (int)fminf(fmaxf(floorf(hs + hbin * (float)g), 0.0f), 62.0f);
}

// Per-wave staged sampling over all t-slices. sbuf is this wave's PRIVATE
// LDS region (no barriers needed; same-wave LDS ops are pipe-ordered).
template<int WPAD>
__device__ __forceinline__ void sample_loop(
    const float* fc,               // wave's channel-pair base (+u0*HWs folded)
    float* sbuf,                   // >= 2*16*(WPAD+1) floats
    const float (*sBt)[4],
    int kcnt, int wbase,
    float hs, float hbin,
    int lane, int hg, int w0,
    float w00, float w01, float w10, float w11,
    float oA[4], float oB[4])
{
    constexpr int STR  = WPAD + 1;     // padded row stride (floats)
    constexpr int TILE = 16 * STR;     // per-channel tile
    constexpr int NL   = (WPAD == 16) ? 2 : 4;   // dwordx4 loads per slice

    // ---- per-lane staging offsets (computed once) ----
    int goffA, goffB = 0, woff;
    if constexpr (WPAD == 16) {
        // instr i = channel i; 64 lanes = 16 rows x 4 units(16B)
        const int dh   = (lane >> 2) & 1;
        const int unit = lane & 3;
        const int hh   = h0_of(hs, hbin, lane >> 3);
        goffA = (hh + dh) * W_SZ + wbase + unit * 4;
        woff  = (lane >> 2) * STR + unit * 4;
    } else {
        // instr i: ch=i>>1, rows (i&1)*8 + (lane>>3); 8 units(16B)/row
        const int dh   = (lane >> 3) & 1;
        const int unit = lane & 7;
        const int hA   = h0_of(hs, hbin, lane >> 4);
        const int hB   = h0_of(hs, hbin, 4 + (lane >> 4));
        goffA = (hA + dh) * W_SZ + wbase + unit * 4;
        goffB = (hB + dh) * W_SZ + wbase + unit * 4;
        woff  = (lane >> 3) * STR + unit * 4;
    }
    const int w0l = w0 - wbase;
    const int ro  = hg * 2 * STR + w0l;

    float4 g[NL];
    // ---- prologue: stage slice 0 ----
    if constexpr (WPAD == 16) {
        g[0] = ld4(fc + goffA);
        g[1] = ld4(fc + CSTR + goffA);
        #pragma unroll
        for (int i = 0; i < 2; ++i) {
            float* d = sbuf + i * TILE + woff;
            d[0] = g[i].x; d[1] = g[i].y; d[2] = g[i].z; d[3] = g[i].w;
        }
    } else {
        g[0] = ld4(fc + goffA);
        g[1] = ld4(fc + goffB);
        g[2] = ld4(fc + CSTR + goffA);
        g[3] = ld4(fc + CSTR + goffB);
        #pragma unroll
        for (int i = 0; i < 4; ++i) {
            float* d = sbuf + (i >> 1) * TILE + (i & 1) * 8 * STR + woff;
            d[0] = g[i].x; d[1] = g[i].y; d[2] = g[i].z; d[3] = g[i].w;
        }
    }

    #pragma unroll
    for (int u = 0; u < KMAX; ++u) {
        if (u < kcnt) {                          // scalar branch
            const bool more = (u + 1 < kcnt);
            float4 gn[NL];
            if (more) {                          // load next slice -> VGPR
                const float* fu = fc + (u + 1) * HWs;
                if constexpr (WPAD == 16) {
                    gn[0] = ld4(fu + goffA);
                    gn[1] = ld4(fu + CSTR + goffA);
                } else {
                    gn[0] = ld4(fu + goffA);
                    gn[1] = ld4(fu + goffB);
                    gn[2] = ld4(fu + CSTR + goffA);
                    gn[3] = ld4(fu + CSTR + goffB);
                }
            }
            // ---- compute slice u from LDS ----
            const float4 bb = *(const float4*)sBt[u];
            const float a00 = sbuf[ro],              a01 = sbuf[ro + 1];
            const float a10 = sbuf[ro + STR],        a11 = sbuf[ro + STR + 1];
            const float c00 = sbuf[ro + TILE],       c01 = sbuf[ro + TILE + 1];
            const float c10 = sbuf[ro + TILE + STR], c11 = sbuf[ro + TILE + STR + 1];
            const float bilA = a00 * w00 + a01 * w01 + a10 * w10 + a11 * w11;
            const float bilB = c00 * w00 + c01 * w01 + c10 * w10 + c11 * w11;
            oA[0] += bb.x * bilA; oA[1] += bb.y * bilA;
            oA[2] += bb.z * bilA; oA[3] += bb.w * bilA;
            oB[0] += bb.x * bilB; oB[1] += bb.y * bilB;
            oB[2] += bb.z * bilB; oB[3] += bb.w * bilB;

            if (more) {                          // write next slice -> LDS
                if constexpr (WPAD == 16) {
                    #pragma unroll
                    for (int i = 0; i < 2; ++i) {
                        float* d = sbuf + i * TILE + woff;
                        d[0] = gn[i].x; d[1] = gn[i].y; d[2] = gn[i].z; d[3] = gn[i].w;
                    }
                } else {
                    #pragma unroll
                    for (int i = 0; i < 4; ++i) {
                        float* d = sbuf + (i >> 1) * TILE + (i & 1) * 8 * STR + woff;
                        d[0] = gn[i].x; d[1] = gn[i].y; d[2] = gn[i].z; d[3] = gn[i].w;
                    }
                }
            }
        }
    }
}

__global__ __launch_bounds__(256, 6) void roialign3d_kernel(
    const float* __restrict__ features,
    const float* __restrict__ rois,
    float* __restrict__ out)
{
    // XCD-phased decode: 4 super-rounds x (1024 rois x 8 chunk-lanes).
    const int bid   = blockIdx.x;
    const int sr    = bid >> 13;
    const int rem   = bid & 8191;
    const int r     = rem >> 3;
    const int chunk = (sr << 3) | (rem & 7);
    const int c0    = chunk * CH;

    const int tid  = threadIdx.x;
    const int lane = tid & 63;
    const int wid  = __builtin_amdgcn_readfirstlane(tid >> 6);
    const int hg   = lane >> 3;
    const int wg   = lane & 7;

    __shared__ __align__(16) float sB[KMAX][4];
    __shared__ int sU0, sK;
    __shared__ float stg[4][2 * 16 * 33];      // 4 waves x 1056 floats = 16.9 KB

    const float* roi = rois + r * 7;
    const int   b   = __builtin_amdgcn_readfirstlane((int)roi[0]);
    const float rx1 = roi[1], ry1 = roi[2];
    const float rx2 = roi[4], ry2 = roi[5];

    // ---- t-coefficient table: built once by threads 0..9 ----
    if (tid < KMAX) {
        const float rt1 = roi[3], rt2 = roi[6];
        const float tbin = fmaxf(rt2 - rt1, 0.0f) * 0.25f;
        int t0a[TGN]; float tw0a[TGN], tw1a[TGN];
        #pragma unroll
        for (int i = 0; i < TGN; ++i) {
            float c  = rt1 + tbin * (float)i;
            float lo = fminf(fmaxf(floorf(c), 0.0f), 14.0f);
            float f  = c - lo;
            float v  = (c >= 0.0f && c < 16.0f) ? 0.125f : 0.0f;
            t0a[i]  = (int)lo;
            tw0a[i] = v * (1.0f - f);
            tw1a[i] = v * f;
        }
        const int u0 = t0a[0];
        const int s0 = u0 + tid;
        float av[TGN];
        #pragma unroll
        for (int i = 0; i < TGN; ++i)
            av[i] = (t0a[i] == s0 ? tw0a[i] : 0.0f)
                  + (t0a[i] + 1 == s0 ? tw1a[i] : 0.0f);
        sB[tid][0] = av[0] + av[1];
        sB[tid][1] = av[1] + av[2];
        sB[tid][2] = av[2] + av[3];
        sB[tid][3] = av[3] + av[4];
        if (tid == 0) { sU0 = u0; sK = t0a[TGN - 1] + 2 - u0; }
    }

    // ---- per-lane h axis ----
    const float hs = ry1 * 0.0625f, he = ry2 * 0.0625f;
    const float hbin = fmaxf(he - hs, 0.0f) * (1.0f / 7.0f);
    const float hc  = hs + hbin * (float)hg;
    const float hlo = fminf(fmaxf(floorf(hc), 0.0f), 62.0f);
    const float hf  = hc - hlo;
    const float hv  = (hc >= 0.0f && hc < 64.0f) ? 1.0f : 0.0f;
    const int   h0  = (int)hlo;
    const float hw0 = hv * (1.0f - hf), hw1 = hv * hf;

    // ---- per-lane w axis ----
    const float wss = rx1 * 0.0625f, wee = rx2 * 0.0625f;
    const float wbin = fmaxf(wee - wss, 0.0f) * (1.0f / 7.0f);
    const float wc  = wss + wbin * (float)wg;
    const float wlo = fminf(fmaxf(floorf(wc), 0.0f), 62.0f);
    const float wf  = wc - wlo;
    const float wv  = (wc >= 0.0f && wc < 64.0f) ? 1.0f : 0.0f;
    const int   w0  = (int)wlo;
    const float ww0 = wv * (1.0f - wf), ww1 = wv * wf;

    const float w00 = hw0 * ww0, w01 = hw0 * ww1;
    const float w10 = hw1 * ww0, w11 = hw1 * ww1;

    __syncthreads();
    const int u0   = __builtin_amdgcn_readfirstlane(sU0);
    const int kcnt = __builtin_amdgcn_readfirstlane(sK);   // in [2, 10]

    // ---- block-uniform w-footprint -> pick WPAD path ----
    const int w0min = (int)fminf(fmaxf(floorf(wss), 0.0f), 62.0f);
    const int w0max = (int)fminf(fmaxf(floorf(wss + 7.0f * wbin), 0.0f), 62.0f);
    const int wb16  = min(w0min & ~3, H_SZ - 16);          // 16B-aligned base
    const int wb32  = min(w0min & ~3, H_SZ - 32);
    const bool use16 = (w0max - wb16) <= 14;               // w0l+1 <= 15

    const float* fc = features
        + ((size_t)b * C_CH + (size_t)(c0 + wid * 2)) * CSTR
        + (size_t)u0 * HWs;

    float oA[4] = {0.f, 0.f, 0.f, 0.f};
    float oB[4] = {0.f, 0.f, 0.f, 0.f};

    if (use16)
        sample_loop<16>(fc, stg[wid], sB, kcnt, wb16, hs, hbin,
                        lane, hg, w0, w00, w01, w10, w11, oA, oB);
    else
        sample_loop<32>(fc, stg[wid], sB, kcnt, wb32, hs, hbin,
                        lane, hg, w0, w00, w01, w10, w11, oA, oB);

    // ---- pool W/H via shuffles; masked nontemporal store (x2 channels) ----
    const bool active = (hg < 7) && (wg < 7);
    const int  s_hw   = hg * 7 + wg;
    float* ob = out + ((size_t)r * C_CH + (size_t)(c0 + wid * 2)) * NOUT;
    #pragma unroll
    for (int td = 0; td < 4; ++td) {
        float o = oA[td];
        o += __shfl_down(o, 1);
        o += __shfl_down(o, 8);
        if (active) __builtin_nontemporal_store(o, &ob[td * 49 + s_hw]);
    }
    ob += NOUT;
    #pragma unroll
    for (int td = 0; td < 4; ++td) {
        float o = oB[td];
        o += __shfl_down(o, 1);
        o += __shfl_down(o, 8);
        if (active) __builtin_nontemporal_store(o, &ob[td * 49 + s_hw]);
    }
}

extern "C" void kernel_launch(void* const* d_in, const int* in_sizes, int n_in,
                              void* d_out, int out_size, void* d_ws, size_t ws_size,
                              hipStream_t stream) {
    const float* features = (const float*)d_in[0];
    const float* rois     = (const float*)d_in[1];
    float* out            = (float*)d_out;

    int R = in_sizes[1] / 7;   // 1024
    int nblocks = R * (C_CH / CH);
    hipLaunchKernelGGL(roialign3d_kernel, dim3(nblocks), dim3(256), 0, stream,
                       features, rois, out);
}

// Round 9
// 129.749 us; speedup vs baseline: 1.2700x; 1.2700x over previous
//
#include <hip/hip_runtime.h>

#define C_CH 256
#define T_SZ 16
#define H_SZ 64
#define W_SZ 64
#define TGN 5
#define CH 8
#define HWs (H_SZ * W_SZ)          // 4096
#define CSTR (T_SZ * HWs)          // 65536
#define NOUT 196
#define KMAX 10                    // max unique t-slices

// Force a single global_load_dwordx2 even though w0 is only 4B-aligned.
// gfx950 HW supports unaligned global loads; the 8B-alignment assumption is
// a codegen hint only (addresses stay 4B-aligned; ~1/16 of lanes cross a
// 64B line, handled by HW).
__device__ __forceinline__ float2 ld2a(const float* p) {
    const float2* q = (const float2*)__builtin_assume_aligned(p, 8);
    return *q;
}

__global__ __launch_bounds__(256, 8) void roialign3d_kernel(
    const float* __restrict__ features,
    const float* __restrict__ rois,
    float* __restrict__ out)
{
    // XCD-phased decode: 4 super-rounds x (1024 rois x 8 chunk-lanes).
    const int bid   = blockIdx.x;
    const int sr    = bid >> 13;
    const int rem   = bid & 8191;
    const int r     = rem >> 3;
    const int chunk = (sr << 3) | (rem & 7);
    const int c0    = chunk * CH;

    const int tid  = threadIdx.x;
    const int lane = tid & 63;
    const int wid  = __builtin_amdgcn_readfirstlane(tid >> 6);
    const int hg   = lane >> 3;    // fixed (h,w) grid point per lane
    const int wg   = lane & 7;

    __shared__ __align__(16) float sB[KMAX][4];   // pooled-T coeff per slice
    __shared__ int sU0, sK;

    const float* roi = rois + r * 7;
    const int   b   = __builtin_amdgcn_readfirstlane((int)roi[0]);
    const float rx1 = roi[1], ry1 = roi[2];
    const float rx2 = roi[4], ry2 = roi[5];

    // ---- t-coefficient table: built once by threads 0..9 ----
    if (tid < KMAX) {
        const float rt1 = roi[3], rt2 = roi[6];
        const float tbin = fmaxf(rt2 - rt1, 0.0f) * 0.25f;
        int t0a[TGN]; float tw0a[TGN], tw1a[TGN];
        #pragma unroll
        for (int i = 0; i < TGN; ++i) {
            float c  = rt1 + tbin * (float)i;
            float lo = fminf(fmaxf(floorf(c), 0.0f), 14.0f);
            float f  = c - lo;
            float v  = (c >= 0.0f && c < 16.0f) ? 0.125f : 0.0f;  // valid * 1/8
            t0a[i]  = (int)lo;
            tw0a[i] = v * (1.0f - f);
            tw1a[i] = v * f;
        }
        const int u0 = t0a[0];
        const int s0 = u0 + tid;
        float av[TGN];
        #pragma unroll
        for (int i = 0; i < TGN; ++i)
            av[i] = (t0a[i] == s0 ? tw0a[i] : 0.0f)
                  + (t0a[i] + 1 == s0 ? tw1a[i] : 0.0f);
        sB[tid][0] = av[0] + av[1];
        sB[tid][1] = av[1] + av[2];
        sB[tid][2] = av[2] + av[3];
        sB[tid][3] = av[3] + av[4];
        if (tid == 0) { sU0 = u0; sK = t0a[TGN - 1] + 2 - u0; }
    }

    // ---- per-lane h axis ----
    const float hs = ry1 * 0.0625f, he = ry2 * 0.0625f;
    const float hbin = fmaxf(he - hs, 0.0f) * (1.0f / 7.0f);
    const float hc  = hs + hbin * (float)hg;
    const float hlo = fminf(fmaxf(floorf(hc), 0.0f), 62.0f);
    const float hf  = hc - hlo;
    const float hv  = (hc >= 0.0f && hc < 64.0f) ? 1.0f : 0.0f;
    const int   h0  = (int)hlo;
    const float hw0 = hv * (1.0f - hf), hw1 = hv * hf;

    // ---- per-lane w axis ----
    const float wss = rx1 * 0.0625f, wee = rx2 * 0.0625f;
    const float wbin = fmaxf(wee - wss, 0.0f) * (1.0f / 7.0f);
    const float wc  = wss + wbin * (float)wg;
    const float wlo = fminf(fmaxf(floorf(wc), 0.0f), 62.0f);
    const float wf  = wc - wlo;
    const float wv  = (wc >= 0.0f && wc < 64.0f) ? 1.0f : 0.0f;
    const int   w0  = (int)wlo;
    const float ww0 = wv * (1.0f - wf), ww1 = wv * wf;

    const float w00 = hw0 * ww0, w01 = hw0 * ww1;
    const float w10 = hw1 * ww0, w11 = hw1 * ww1;
    const int hw_off = h0 * W_SZ + w0;

    __syncthreads();
    const int u0   = __builtin_amdgcn_readfirstlane(sU0);
    const int kcnt = __builtin_amdgcn_readfirstlane(sK);   // in [2, 10]

    const bool active = (hg < 7) && (wg < 7);
    const int  s_hw   = hg * 7 + wg;

    const float* fcA = features
        + ((size_t)b * C_CH + (size_t)(c0 + wid * 2)) * CSTR
        + (size_t)u0 * HWs + hw_off;
    const float* fcB = fcA + CSTR;

    float oA[4] = {0.f, 0.f, 0.f, 0.f};
    float oB[4] = {0.f, 0.f, 0.f, 0.f};

    #pragma unroll
    for (int u = 0; u < KMAX; ++u) {
        if (u < 2 || u < kcnt) {               // scalar branch (kcnt >= 2)
            const float4 bb = *(const float4*)sB[u];   // uniform broadcast
            const float* pA = fcA + u * HWs;
            const float* pB = fcB + u * HWs;
            float2 rA0 = ld2a(pA);
            float2 rA1 = ld2a(pA + W_SZ);
            float2 rB0 = ld2a(pB);
            float2 rB1 = ld2a(pB + W_SZ);

            const float bilA = rA0.x * w00 + rA0.y * w01 + rA1.x * w10 + rA1.y * w11;
            const float bilB = rB0.x * w00 + rB0.y * w01 + rB1.x * w10 + rB1.y * w11;

            oA[0] += bb.x * bilA; oA[1] += bb.y * bilA;
            oA[2] += bb.z * bilA; oA[3] += bb.w * bilA;
            oB[0] += bb.x * bilB; oB[1] += bb.y * bilB;
            oB[2] += bb.z * bilB; oB[3] += bb.w * bilB;
        }
    }

    // ---- pool W/H via shuffles; masked nontemporal store (x2 channels) ----
    float* ob = out + ((size_t)r * C_CH + (size_t)(c0 + wid * 2)) * NOUT;
    #pragma unroll
    for (int td = 0; td < 4; ++td) {
        float o = oA[td];
        o += __shfl_down(o, 1);
        o += __shfl_down(o, 8);
        if (active) __builtin_nontemporal_store(o, &ob[td * 49 + s_hw]);
    }
    ob += NOUT;
    #pragma unroll
    for (int td = 0; td < 4; ++td) {
        float o = oB[td];
        o += __shfl_down(o, 1);
        o += __shfl_down(o, 8);
        if (active) __builtin_nontemporal_store(o, &ob[td * 49 + s_hw]);
    }
}

extern "C" void kernel_launch(void* const* d_in, const int* in_sizes, int n_in,
                              void* d_out, int out_size, void* d_ws, size_t ws_size,
                              hipStream_t stream) {
    const float* features = (const float*)d_in[0];
    const float* rois     = (const float*)d_in[1];
    float* out            = (float*)d_out;

    int R = in_sizes[1] / 7;   // 1024
    int nblocks = R * (C_CH / CH);
    hipLaunchKernelGGL(roialign3d_kernel, dim3(nblocks), dim3(256), 0, stream,
                       features, rois, out);
}